// Round 1
// baseline (1401.246 us; speedup 1.0000x reference)
//
#include <hip/hip_runtime.h>
#include <math.h>

#define BATCH 4096
#define HID   1024
#define KDIM  1024
#define NSTEP 15        // TIME_LIMIT - 1 scan steps

// GEMM tiling: C-tile 128 rows x 64 cols, BK=16, 256 threads, 8x4 microtile
#define TM 128
#define TN 64
#define BK 16
#define LDA (TM + 4)    // k-major LDS plane stride, pad 4 -> bank rotation, keeps float4 align
#define LDB (TN + 4)

__global__ __launch_bounds__(256) void setup_kernel(int* __restrict__ list0,
                                                    int* __restrict__ counts,
                                                    float* __restrict__ halt_accum,
                                                    float* __restrict__ tot_rem) {
    int i = blockIdx.x * 256 + threadIdx.x;   // grid 16 -> 4096 threads
    if (i < BATCH) { list0[i] = i; halt_accum[i] = 0.f; tot_rem[i] = 0.f; }
    if (i < 16) counts[i] = (i == 0) ? BATCH : 0;
}

// W_ih is (1024, 1025): repack first 1024 cols contiguously, last col -> flagcol
__global__ __launch_bounds__(256) void repack_kernel(const float* __restrict__ W_ih,
                                                     float* __restrict__ W,
                                                     float* __restrict__ flagcol) {
    int idx = blockIdx.x * 256 + threadIdx.x;   // grid 4096 -> 1M threads
    int j = idx >> 10, i = idx & 1023;
    W[idx] = W_ih[j * 1025 + i];
    if (idx < 1024) flagcol[idx] = W_ih[idx * 1025 + 1024];
}

// mode 0: Cout[row] = A[row] @ B^T + bias               (x_base)
// mode 1: Cout[row] = tanh(acc + xbase[row] + flag*flagcol + bias)   (recurrent step)
// Rows gathered through `list` (nullptr = identity); blocks beyond *pcount exit.
__global__ __launch_bounds__(256) void gemm_kernel(
    const float* __restrict__ A, const float* __restrict__ B,
    const float* __restrict__ bias,
    const float* __restrict__ xbase, const float* __restrict__ flagcol, float flag,
    const int* __restrict__ list, const int* __restrict__ pcount,
    float* __restrict__ Cout, int mode) {
    int count = pcount ? *pcount : BATCH;
    int row0 = blockIdx.x * TM;
    if (row0 >= count) return;
    int col0 = blockIdx.y * TN;

    __shared__ float As[BK][LDA];
    __shared__ float Bs[BK][LDB];

    int t = threadIdx.x;
    int tx = t & 15, ty = t >> 4;

    // A-tile staging: 128 rows x 4 float4-cols = 512 slots, 2 per thread
    const float* aptr[2];
    int arow[2], akq[2];
#pragma unroll
    for (int l = 0; l < 2; l++) {
        int s = t + l * 256;
        int r = s >> 2, kq = s & 3;
        arow[l] = r; akq[l] = kq;
        int rr = row0 + r;
        int grow = 0;
        if (rr < count) grow = list ? list[rr] : rr;   // OOB rows read row 0 (never stored)
        aptr[l] = A + (size_t)grow * KDIM + kq * 4;
    }
    // B-tile staging: 64 rows x 4 float4-cols = 256 slots, 1 per thread
    int brow = t >> 2, bkq = t & 3;
    const float* bptr = B + (size_t)(col0 + brow) * KDIM + bkq * 4;

    float acc[8][4];
#pragma unroll
    for (int i = 0; i < 8; i++)
#pragma unroll
        for (int j = 0; j < 4; j++) acc[i][j] = 0.f;

    for (int k0 = 0; k0 < KDIM; k0 += BK) {
        float4 av0 = *(const float4*)(aptr[0] + k0);
        float4 av1 = *(const float4*)(aptr[1] + k0);
        float4 bv  = *(const float4*)(bptr + k0);
        __syncthreads();
        As[akq[0] * 4 + 0][arow[0]] = av0.x;
        As[akq[0] * 4 + 1][arow[0]] = av0.y;
        As[akq[0] * 4 + 2][arow[0]] = av0.z;
        As[akq[0] * 4 + 3][arow[0]] = av0.w;
        As[akq[1] * 4 + 0][arow[1]] = av1.x;
        As[akq[1] * 4 + 1][arow[1]] = av1.y;
        As[akq[1] * 4 + 2][arow[1]] = av1.z;
        As[akq[1] * 4 + 3][arow[1]] = av1.w;
        Bs[bkq * 4 + 0][brow] = bv.x;
        Bs[bkq * 4 + 1][brow] = bv.y;
        Bs[bkq * 4 + 2][brow] = bv.z;
        Bs[bkq * 4 + 3][brow] = bv.w;
        __syncthreads();
#pragma unroll
        for (int k = 0; k < BK; k++) {
            float4 a0 = *(const float4*)&As[k][ty * 8];
            float4 a1 = *(const float4*)&As[k][ty * 8 + 4];
            float4 b0 = *(const float4*)&Bs[k][tx * 4];
            float a[8] = {a0.x, a0.y, a0.z, a0.w, a1.x, a1.y, a1.z, a1.w};
            float b[4] = {b0.x, b0.y, b0.z, b0.w};
#pragma unroll
            for (int i = 0; i < 8; i++)
#pragma unroll
                for (int j = 0; j < 4; j++)
                    acc[i][j] = fmaf(a[i], b[j], acc[i][j]);
        }
    }

#pragma unroll
    for (int i = 0; i < 8; i++) {
        int rr = row0 + ty * 8 + i;
        if (rr >= count) continue;
        int grow = list ? list[rr] : rr;
        int col = col0 + tx * 4;
        float4 bv = *(const float4*)(bias + col);
        float4 res;
        if (mode == 0) {
            res.x = acc[i][0] + bv.x;
            res.y = acc[i][1] + bv.y;
            res.z = acc[i][2] + bv.z;
            res.w = acc[i][3] + bv.w;
        } else {
            float4 xb = *(const float4*)(xbase + (size_t)grow * KDIM + col);
            float4 fc = *(const float4*)(flagcol + col);
            res.x = tanhf(acc[i][0] + xb.x + flag * fc.x + bv.x);
            res.y = tanhf(acc[i][1] + xb.y + flag * fc.y + bv.y);
            res.z = tanhf(acc[i][2] + xb.z + flag * fc.z + bv.z);
            res.w = tanhf(acc[i][3] + xb.w + flag * fc.w + bv.w);
        }
        *(float4*)(Cout + (size_t)grow * KDIM + col) = res;
    }
}

// One wave per active row: halt logit, sigmoid, halting state machine,
// tot_h accumulation into d_out, compaction of next-step list.
__global__ __launch_bounds__(256) void halt_kernel(
    const float* __restrict__ h, const float* __restrict__ W_halt,
    const float* __restrict__ b_halt,
    const int* __restrict__ list, const int* __restrict__ pcount,
    int* __restrict__ list_next, int* __restrict__ pcount_next,
    float* __restrict__ halt_accum, float* __restrict__ tot_rem,
    float* __restrict__ tot_h, float* __restrict__ steps_out,
    int stepnum, int first) {
    int count = *pcount;
    int wid = threadIdx.x >> 6, lane = threadIdx.x & 63;
    int r = blockIdx.x * 4 + wid;
    if (r >= count) return;
    int row = list[r];
    const float* hr = h + (size_t)row * HID;

    float dot = 0.f;
#pragma unroll
    for (int q = 0; q < 4; q++) {
        int c = q * 256 + lane * 4;
        float4 hv = *(const float4*)(hr + c);
        float4 wv = *(const float4*)(W_halt + c);
        dot += hv.x * wv.x + hv.y * wv.y + hv.z * wv.z + hv.w * wv.w;
    }
#pragma unroll
    for (int off = 32; off > 0; off >>= 1) dot += __shfl_down(dot, off);

    float combined = 0.f;
    if (lane == 0) {
        float p = 1.f / (1.f + expf(-(dot + b_halt[0])));
        float S = halt_accum[row] + p;      // halt_accum += masked_halt (row is cont)
        halt_accum[row] = S;
        tot_rem[row] += p;
        bool ending = (S + p) > 0.99f;      // budget = 1 - PONDER_EPS
        if (ending) {
            combined = p + (1.f - S);       // masked_halt + masked_rem
            steps_out[row] = (float)stepnum; // tot_steps+1 for a row ending at step n is n
        } else {
            combined = p;
            int idx = atomicAdd(pcount_next, 1);
            list_next[idx] = row;
        }
    }
    combined = __shfl(combined, 0);

    float* th = tot_h + (size_t)row * HID;
#pragma unroll
    for (int q = 0; q < 4; q++) {
        int c = q * 256 + lane * 4;
        float4 hv = *(const float4*)(hr + c);
        float4 ov;
        if (first) {
            ov.x = combined * hv.x; ov.y = combined * hv.y;
            ov.z = combined * hv.z; ov.w = combined * hv.w;
        } else {
            ov = *(const float4*)(th + c);
            ov.x += combined * hv.x; ov.y += combined * hv.y;
            ov.z += combined * hv.z; ov.w += combined * hv.w;
        }
        *(float4*)(th + c) = ov;
    }
}

// Survivors after all 15 steps: tot_h += (1 - halt_accum) * h_final; steps = 16
__global__ __launch_bounds__(256) void epilogue_kernel(
    const float* __restrict__ h, const int* __restrict__ list,
    const int* __restrict__ pcount, const float* __restrict__ halt_accum,
    float* __restrict__ tot_h, float* __restrict__ steps_out) {
    int count = *pcount;
    int wid = threadIdx.x >> 6, lane = threadIdx.x & 63;
    int r = blockIdx.x * 4 + wid;
    if (r >= count) return;
    int row = list[r];
    float cmb = 1.f - halt_accum[row];
    if (lane == 0) steps_out[row] = 16.f;
    const float* hr = h + (size_t)row * HID;
    float* th = tot_h + (size_t)row * HID;
#pragma unroll
    for (int q = 0; q < 4; q++) {
        int c = q * 256 + lane * 4;
        float4 hv = *(const float4*)(hr + c);
        float4 ov = *(const float4*)(th + c);
        ov.x += cmb * hv.x; ov.y += cmb * hv.y;
        ov.z += cmb * hv.z; ov.w += cmb * hv.w;
        *(float4*)(th + c) = ov;
    }
}

__global__ __launch_bounds__(256) void ponder_kernel(const float* __restrict__ tot_rem,
                                                     float* __restrict__ out) {
    __shared__ float s[4];
    float v = 0.f;
#pragma unroll
    for (int i = 0; i < 16; i++) v += tot_rem[threadIdx.x + i * 256];
#pragma unroll
    for (int off = 32; off > 0; off >>= 1) v += __shfl_down(v, off);
    int lane = threadIdx.x & 63, wid = threadIdx.x >> 6;
    if (lane == 0) s[wid] = v;
    __syncthreads();
    if (threadIdx.x == 0) out[0] = (s[0] + s[1] + s[2] + s[3]) * (-0.01f / 4096.f);
}

extern "C" void kernel_launch(void* const* d_in, const int* in_sizes, int n_in,
                              void* d_out, int out_size, void* d_ws, size_t ws_size,
                              hipStream_t stream) {
    const float* inputs = (const float*)d_in[0];
    const float* hidden = (const float*)d_in[1];
    const float* W_ih   = (const float*)d_in[2];
    const float* b_ih   = (const float*)d_in[3];
    const float* W_hh   = (const float*)d_in[4];
    const float* b_hh   = (const float*)d_in[5];
    const float* W_halt = (const float*)d_in[6];
    const float* b_halt = (const float*)d_in[7];
    float* out = (float*)d_out;

    float* ws = (float*)d_ws;
    float* xbase = ws;                                   // 4096*1024
    float* h0 = xbase + (size_t)BATCH * HID;             // 4096*1024
    float* h1 = h0 + (size_t)BATCH * HID;                // 4096*1024
    float* W  = h1 + (size_t)BATCH * HID;                // 1024*1024 repacked W_ih
    float* flagcol = W + (size_t)KDIM * KDIM;            // 1024
    float* halt_accum = flagcol + KDIM;                  // 4096
    float* tot_rem = halt_accum + BATCH;                 // 4096
    int* list0 = (int*)(tot_rem + BATCH);                // 4096 ints
    int* list1 = list0 + BATCH;                          // 4096 ints
    int* counts = list1 + BATCH;                         // 16 ints

    float* hb[2] = {h0, h1};
    int* lists[2] = {list0, list1};

    float* tot_h = out;                                  // 4096*1024
    float* ponder = out + (size_t)BATCH * HID;           // 1
    float* steps_out = ponder + 1;                       // 4096

    setup_kernel<<<16, 256, 0, stream>>>(list0, counts, halt_accum, tot_rem);
    repack_kernel<<<4096, 256, 0, stream>>>(W_ih, W, flagcol);

    // x_base = inputs @ W_ih[:, :-1].T + b_ih
    gemm_kernel<<<dim3(32, 16), 256, 0, stream>>>(inputs, W, b_ih, nullptr, nullptr, 0.f,
                                                  nullptr, nullptr, xbase, 0);
    for (int t = 0; t < NSTEP; t++) {
        const float* hprev = (t == 0) ? hidden : hb[(t - 1) & 1];
        gemm_kernel<<<dim3(32, 16), 256, 0, stream>>>(hprev, W_hh, b_hh, xbase, flagcol,
                                                      (t == 0) ? 1.f : 0.f,
                                                      lists[t & 1], counts + t, hb[t & 1], 1);
        halt_kernel<<<1024, 256, 0, stream>>>(hb[t & 1], W_halt, b_halt,
                                              lists[t & 1], counts + t,
                                              lists[(t + 1) & 1], counts + t + 1,
                                              halt_accum, tot_rem, tot_h, steps_out,
                                              t + 1, (t == 0) ? 1 : 0);
    }
    epilogue_kernel<<<1024, 256, 0, stream>>>(hb[0], lists[1], counts + 15,
                                              halt_accum, tot_h, steps_out);
    ponder_kernel<<<1, 256, 0, stream>>>(tot_rem, ponder);
}